// Round 6
// baseline (633.501 us; speedup 1.0000x reference)
//
#include <hip/hip_runtime.h>
#include <cstdint>
#include <cstddef>

#define BB 64
#define TT 512
#define DD 1024
#define NTAG 64
#define SCORES_ELEMS (BB * TT * NTAG)      // 2097152
#define TAGS_OFF SCORES_ELEMS              // 2097152
#define LOSS_OFF (SCORES_ELEMS + BB * TT)  // 2130920

__device__ __forceinline__ float rl(float v, int i) {
  return __int_as_float(__builtin_amdgcn_readlane(__float_as_int(v), i));
}

// ---------------- DPP wave64 reductions ----------------
__device__ __forceinline__ float dpp_red_max(float v) {
  int x;
  x = __builtin_amdgcn_update_dpp(__float_as_int(v), __float_as_int(v), 0x111, 0xf, 0xf, false);
  v = fmaxf(v, __int_as_float(x));
  x = __builtin_amdgcn_update_dpp(__float_as_int(v), __float_as_int(v), 0x112, 0xf, 0xf, false);
  v = fmaxf(v, __int_as_float(x));
  x = __builtin_amdgcn_update_dpp(__float_as_int(v), __float_as_int(v), 0x114, 0xf, 0xf, false);
  v = fmaxf(v, __int_as_float(x));
  x = __builtin_amdgcn_update_dpp(__float_as_int(v), __float_as_int(v), 0x118, 0xf, 0xf, false);
  v = fmaxf(v, __int_as_float(x));
  x = __builtin_amdgcn_update_dpp(__float_as_int(v), __float_as_int(v), 0x142, 0xa, 0xf, false);
  v = fmaxf(v, __int_as_float(x));
  x = __builtin_amdgcn_update_dpp(__float_as_int(v), __float_as_int(v), 0x143, 0xc, 0xf, false);
  v = fmaxf(v, __int_as_float(x));
  return __int_as_float(__builtin_amdgcn_readlane(__float_as_int(v), 63));
}

__device__ __forceinline__ float dpp_red_sum(float v) {
  int x;
  x = __builtin_amdgcn_update_dpp(__float_as_int(v), __float_as_int(v), 0x111, 0xf, 0xf, false);
  v = v + __int_as_float(x);
  x = __builtin_amdgcn_update_dpp(__float_as_int(v), __float_as_int(v), 0x112, 0xf, 0xf, false);
  v = v + __int_as_float(x);
  x = __builtin_amdgcn_update_dpp(__float_as_int(v), __float_as_int(v), 0x114, 0xf, 0xf, false);
  v = v + __int_as_float(x);
  x = __builtin_amdgcn_update_dpp(__float_as_int(v), __float_as_int(v), 0x118, 0xf, 0xf, false);
  v = v + __int_as_float(x);
  x = __builtin_amdgcn_update_dpp(__float_as_int(v), __float_as_int(v), 0x142, 0xa, 0xf, false);
  v = v + __int_as_float(x);
  x = __builtin_amdgcn_update_dpp(__float_as_int(v), __float_as_int(v), 0x143, 0xc, 0xf, false);
  v = v + __int_as_float(x);
  return __int_as_float(__builtin_amdgcn_readlane(__float_as_int(v), 63));
}

// ---------------- Kernel 1: scores = (X @ W + b) * mask ----------------
// 1024 blocks x 256 thr. Tile 32 rows x 64 cols; 4 waves split K (256 k each,
// no main-loop barriers). Per-lane 4x8 acc. W read DIRECTLY from global
// (L2-resident 256KB) -> LDS pipe only carries X (1 ds_read_b128 per k per
// wave = 0.375 LDS-cyc/FMA < 0.5 VALU-cyc/FMA: VALU-bound). 4 blocks/CU.
__global__ __launch_bounds__(256, 4) void gemm_scores(
    const float* __restrict__ X, const int* __restrict__ mask,
    const float* __restrict__ W, const float* __restrict__ bias,
    float* __restrict__ scores) {
  __shared__ float smem[4096];  // [0,2048): X stage 4 waves x 512; [2048,4096): psum 32x64
  const int tid = threadIdx.x;
  const int lane = tid & 63;
  const int wv = tid >> 6;
  const int row0 = blockIdx.x * 32;
  const int kbase = wv * 256;
  float* psum = smem + 2048;

  {  // zero psum
    const float4 z4 = make_float4(0.f, 0.f, 0.f, 0.f);
    *reinterpret_cast<float4*>(&psum[tid * 8]) = z4;
    *reinterpret_cast<float4*>(&psum[tid * 8 + 4]) = z4;
  }
  __syncthreads();

  float* smx = smem + wv * 512;  // [16 k][32 rows]

  const int lr = lane & 7;        // row-group (4 rows)
  const int lc = lane >> 3;       // col-group (8 cols)
  const int lc8 = lc * 8;
  const int srow = lane & 31;     // staging row
  const int skh = (lane >> 5) * 8;  // staging k-half: 0 or 8

  float acc[4][8];
#pragma unroll
  for (int i = 0; i < 4; ++i)
#pragma unroll
    for (int j = 0; j < 8; ++j) acc[i][j] = 0.f;

  const float* Xb = X + (size_t)row0 * DD + kbase;
  const float* Wb = W + (size_t)kbase * NTAG;

  float4 px[2];
#pragma unroll
  for (int p = 0; p < 2; ++p)
    px[p] = *reinterpret_cast<const float4*>(Xb + (size_t)srow * DD + skh + p * 4);

  for (int c = 0; c < 16; ++c) {
    // stage X chunk [16k][32rows] (same-wave in-order, no barrier)
#pragma unroll
    for (int p = 0; p < 2; ++p) {
      smx[(skh + p * 4 + 0) * 32 + srow] = px[p].x;
      smx[(skh + p * 4 + 1) * 32 + srow] = px[p].y;
      smx[(skh + p * 4 + 2) * 32 + srow] = px[p].z;
      smx[(skh + p * 4 + 3) * 32 + srow] = px[p].w;
    }
    const int cn = (c < 15) ? (c + 1) : 0;  // dummy reload on last iter (in-bounds)
#pragma unroll
    for (int p = 0; p < 2; ++p)
      px[p] = *reinterpret_cast<const float4*>(
          Xb + (size_t)srow * DD + cn * 16 + skh + p * 4);

    const float* Wc = Wb + c * 1024;  // 16 k x 64 cols
#pragma unroll
    for (int k = 0; k < 16; ++k) {
      const float4 xa = *reinterpret_cast<const float4*>(&smx[k * 32 + lr * 4]);
      const float4 wa = *reinterpret_cast<const float4*>(Wc + k * 64 + lc8);
      const float4 wb2 = *reinterpret_cast<const float4*>(Wc + k * 64 + lc8 + 4);
      const float x0 = xa.x, x1 = xa.y, x2 = xa.z, x3 = xa.w;
      const float q0 = wa.x, q1 = wa.y, q2 = wa.z, q3 = wa.w;
      const float q4 = wb2.x, q5 = wb2.y, q6 = wb2.z, q7 = wb2.w;
#define ROW(i, xi)                                                          \
  acc[i][0] = fmaf(xi, q0, acc[i][0]); acc[i][1] = fmaf(xi, q1, acc[i][1]); \
  acc[i][2] = fmaf(xi, q2, acc[i][2]); acc[i][3] = fmaf(xi, q3, acc[i][3]); \
  acc[i][4] = fmaf(xi, q4, acc[i][4]); acc[i][5] = fmaf(xi, q5, acc[i][5]); \
  acc[i][6] = fmaf(xi, q6, acc[i][6]); acc[i][7] = fmaf(xi, q7, acc[i][7]);
      ROW(0, x0) ROW(1, x1) ROW(2, x2) ROW(3, x3)
#undef ROW
    }
  }

  // combine wave partials; bank-staggered by lr -> 2 lanes/bank (free)
#pragma unroll
  for (int i = 0; i < 4; ++i) {
    const int row = lr * 4 + i;
#pragma unroll
    for (int j = 0; j < 8; ++j) {
      const int jj = (j + lr) & 7;
      atomicAdd(&psum[row * 64 + lc8 + jj], acc[i][jj]);
    }
  }
  __syncthreads();

  // epilogue: bias + mask, coalesced float4 stores (8 floats per thread)
  const int f = tid * 8;
  const int row = f >> 6;
  const int col = f & 63;
  const float mf = (float)mask[row0 + row];
#pragma unroll
  for (int g = 0; g < 2; ++g) {
    const float4 p = *reinterpret_cast<float4*>(&psum[f + g * 4]);
    const float4 b4 = *reinterpret_cast<const float4*>(&bias[col + g * 4]);
    float4 o;
    o.x = (p.x + b4.x) * mf;
    o.y = (p.y + b4.y) * mf;
    o.z = (p.z + b4.z) * mf;
    o.w = (p.w + b4.w) * mf;
    *reinterpret_cast<float4*>(&scores[(size_t)(row0 + row) * 64 + col + g * 4]) = o;
  }
}

// ---------------- Kernel 2: forward passes (readlane broadcast) ----------
__global__ __launch_bounds__(64) void crf_forward(
    const float* __restrict__ scores, const int* __restrict__ mask,
    const int* __restrict__ labels, const float* __restrict__ trans,
    const float* __restrict__ startv, const float* __restrict__ endv,
    float* __restrict__ ws_alpha, int* __restrict__ ws_lasttag,
    float* __restrict__ ws_loss) {
  const int lane = threadIdx.x;
  const int role = blockIdx.x >> 6;
  const int b = blockIdx.x & 63;
  const float* sc = scores + (size_t)b * TT * NTAG;
  const int* maskb = mask + b * TT;

  if (role == 0) {
    float tcol[NTAG];  // tcol[i] = trans[i][lane]
#pragma unroll
    for (int i = 0; i < NTAG; ++i) tcol[i] = trans[(size_t)i * NTAG + lane];
    float valpha = startv[lane] + sc[lane];
    float* wsA = ws_alpha + (size_t)b * (TT - 1) * NTAG;

    float e0 = sc[1 * NTAG + lane], e1 = sc[2 * NTAG + lane];
    float e2 = sc[3 * NTAG + lane], e3 = sc[4 * NTAG + lane];
    int k0 = maskb[1], k1 = maskb[2], k2 = maskb[3], k3 = maskb[4];

    for (int t = 1; t < TT; ++t) {
      wsA[(size_t)(t - 1) * NTAG + lane] = valpha;
      const float emit = e0;
      const int m = k0;
      const int tp = (t + 4 < TT) ? (t + 4) : (TT - 1);
      e0 = e1; e1 = e2; e2 = e3;
      e3 = sc[(size_t)tp * NTAG + lane];
      k0 = k1; k1 = k2; k2 = k3;
      k3 = maskb[tp];

      // 4 chains, max3-fusable pairs
      float m0 = -3.4e38f, m1 = -3.4e38f, m2 = -3.4e38f, m3 = -3.4e38f;
#pragma unroll
      for (int i = 0; i < NTAG; i += 8) {
        m0 = fmaxf(m0, fmaxf(rl(valpha, i + 0) + tcol[i + 0], rl(valpha, i + 1) + tcol[i + 1]));
        m1 = fmaxf(m1, fmaxf(rl(valpha, i + 2) + tcol[i + 2], rl(valpha, i + 3) + tcol[i + 3]));
        m2 = fmaxf(m2, fmaxf(rl(valpha, i + 4) + tcol[i + 4], rl(valpha, i + 5) + tcol[i + 5]));
        m3 = fmaxf(m3, fmaxf(rl(valpha, i + 6) + tcol[i + 6], rl(valpha, i + 7) + tcol[i + 7]));
      }
      const float best = fmaxf(fmaxf(m0, m1), fmaxf(m2, m3));
      valpha = m ? (best + emit) : valpha;
    }

    const float fin = valpha + endv[lane];
    const float mx = dpp_red_max(fin);
    const int jlast = (int)__builtin_ctzll(__ballot(fin == mx));
    if (lane == 0) ws_lasttag[b] = jlast;
  } else {
    float ecol[NTAG];  // exp(trans[i][lane])
#pragma unroll
    for (int i = 0; i < NTAG; ++i) ecol[i] = expf(trans[(size_t)i * NTAG + lane]);

    const float alpha0 = startv[lane] + sc[lane];
    const float M0 = dpp_red_max(alpha0);
    float z = expf(alpha0 - M0);  // z = exp(alpha - C)
    float C = M0;

    float e0 = sc[1 * NTAG + lane], e1 = sc[2 * NTAG + lane];
    float e2 = sc[3 * NTAG + lane], e3 = sc[4 * NTAG + lane];
    int k0 = maskb[1], k1 = maskb[2], k2 = maskb[3], k3 = maskb[4];
    float pe = expf(e0);

    for (int t = 1; t < TT; ++t) {
      const float pec = pe;
      const int m = k0;
      const int tp = (t + 4 < TT) ? (t + 4) : (TT - 1);
      e0 = e1; e1 = e2; e2 = e3;
      e3 = sc[(size_t)tp * NTAG + lane];
      k0 = k1; k1 = k2; k2 = k3;
      k3 = maskb[tp];
      pe = expf(e0);  // off critical path

      float s0 = 0.f, s1 = 0.f, s2 = 0.f, s3 = 0.f;
      float s4 = 0.f, s5 = 0.f, s6 = 0.f, s7 = 0.f;
#pragma unroll
      for (int i = 0; i < NTAG; i += 8) {
        s0 = fmaf(rl(z, i + 0), ecol[i + 0], s0);
        s1 = fmaf(rl(z, i + 1), ecol[i + 1], s1);
        s2 = fmaf(rl(z, i + 2), ecol[i + 2], s2);
        s3 = fmaf(rl(z, i + 3), ecol[i + 3], s3);
        s4 = fmaf(rl(z, i + 4), ecol[i + 4], s4);
        s5 = fmaf(rl(z, i + 5), ecol[i + 5], s5);
        s6 = fmaf(rl(z, i + 6), ecol[i + 6], s6);
        s7 = fmaf(rl(z, i + 7), ecol[i + 7], s7);
      }
      const float inner = ((s0 + s1) + (s2 + s3)) + ((s4 + s5) + (s6 + s7));
      z = m ? (inner * pec) : z;

      if ((t & 7) == 0) {  // renormalize; growth bounded, fp32-safe
        const float s = dpp_red_sum(z);
        const float r = __builtin_amdgcn_rcpf(s);
        z *= r;
        C += logf(s);
      }
    }
    const float av = logf(z) + C;
    const float fv = av + endv[lane];
    const float M2 = dpp_red_max(fv);
    const float sSum = dpp_red_sum(expf(fv - M2));
    const float log_z = logf(sSum) + M2;

    float g = 0.f, msumf = 0.f;
    for (int t = lane; t < TT; t += 64) {
      const int lab = labels[b * TT + t];
      const float mf = (float)maskb[t];
      msumf += mf;
      g += sc[(size_t)t * NTAG + lab] * mf;
      if (t >= 1) {
        const int labp = labels[b * TT + t - 1];
        g += trans[(size_t)labp * NTAG + lab] * mf;
      }
    }
    g = dpp_red_sum(g);
    const float msum = dpp_red_sum(msumf);
    const int last_idx = (int)msum - 1;
    g += startv[labels[b * TT]] + endv[labels[b * TT + last_idx]];
    if (lane == 0) ws_loss[b] = log_z - g;
  }
}

// ---------------- Kernel 3: backtrack via on-the-fly recompute ----------
// 64 blocks x 64 thr. Per step: c = alpha_s + trans[lane][jcur] (adds bit-
// identical to forward -> exact max match; ballot+ctz = first-index argmax).
// alpha prefetched 4-deep (regs hold {s..s-3}; refill loads s-4).
__global__ __launch_bounds__(64) void viterbi_bt(
    const float* __restrict__ ws_alpha, const int* __restrict__ ws_lasttag,
    const int* __restrict__ mask, const float* __restrict__ trans,
    float* __restrict__ out_tags) {
  __shared__ float tP[NTAG * 65];  // tP[i*65+j] = trans[i][j]
  __shared__ int mk[TT];
  __shared__ unsigned char tagb[TT];
  const int lane = threadIdx.x;
  const int b = blockIdx.x;

#pragma unroll
  for (int i = 0; i < NTAG; ++i) tP[i * 65 + lane] = trans[(size_t)i * NTAG + lane];
  for (int t = lane; t < TT; t += 64) mk[t] = mask[b * TT + t];
  // single wave: DS ops complete in order; compiler inserts lgkmcnt waits

  const float* wsA = ws_alpha + (size_t)b * (TT - 1) * NTAG;
  int jcur = ws_lasttag[b];
  if (lane == 0) tagb[TT - 1] = (unsigned char)jcur;

  float a0 = wsA[(size_t)(TT - 2) * NTAG + lane];
  float a1 = wsA[(size_t)(TT - 3) * NTAG + lane];
  float a2 = wsA[(size_t)(TT - 4) * NTAG + lane];
  float a3 = wsA[(size_t)(TT - 5) * NTAG + lane];

  for (int s = TT - 2; s >= 0; --s) {
    const float ac = a0;  // alpha_s
    a0 = a1; a1 = a2; a2 = a3;
    const int sp = (s >= 4) ? (s - 4) : 0;  // refill: regs held {s..s-3}; load s-4
    a3 = wsA[(size_t)sp * NTAG + lane];
    if (mk[s + 1]) {
      const float c = ac + tP[lane * 65 + jcur];  // (lane+jcur)%32 banks: free
      const float cmx = dpp_red_max(c);
      jcur = (int)__builtin_ctzll(__ballot(c == cmx));
    }
    if (lane == 0) tagb[s] = (unsigned char)jcur;
  }

  for (int t = lane; t < TT; t += 64)
    out_tags[b * TT + t] = (float)(mk[t] ? (int)tagb[t] : 0);
}

// ---------------- Kernel 4: loss = mean(log_z - gold) ----------------
__global__ __launch_bounds__(64) void loss_mean(const float* __restrict__ ws_loss,
                                                float* __restrict__ out) {
  const float v = ws_loss[threadIdx.x];
  const float s = dpp_red_sum(v);
  if (threadIdx.x == 0) out[0] = s * (1.0f / 64.0f);
}

extern "C" void kernel_launch(void* const* d_in, const int* in_sizes, int n_in,
                              void* d_out, int out_size, void* d_ws, size_t ws_size,
                              hipStream_t stream) {
  const float* X = (const float*)d_in[0];
  const int* mask = (const int*)d_in[1];
  const int* labels = (const int*)d_in[2];
  const float* W = (const float*)d_in[3];
  const float* bias = (const float*)d_in[4];
  const float* trans = (const float*)d_in[5];
  const float* startv = (const float*)d_in[6];
  const float* endv = (const float*)d_in[7];

  float* out = (float*)d_out;
  float* scores = out;
  float* out_tags = out + TAGS_OFF;
  float* out_loss = out + LOSS_OFF;

  float* ws_alpha = (float*)d_ws;  // 64*511*64 floats = 8.37 MB
  int* ws_lasttag = (int*)(ws_alpha + (size_t)BB * (TT - 1) * NTAG);
  float* ws_loss = (float*)(ws_lasttag + BB);

  gemm_scores<<<1024, 256, 0, stream>>>(X, mask, W, bias, scores);
  crf_forward<<<128, 64, 0, stream>>>(scores, mask, labels, trans, startv, endv,
                                      ws_alpha, ws_lasttag, ws_loss);
  viterbi_bt<<<64, 64, 0, stream>>>(ws_alpha, ws_lasttag, mask, trans, out_tags);
  loss_mean<<<1, 64, 0, stream>>>(ws_loss, out_loss);
}